// Round 12
// baseline (546.187 us; speedup 1.0000x reference)
//
#include <hip/hip_runtime.h>

#define D_     784
#define ROWS   8
#define NCLS   10
#define BLOCK  768              // 12 waves; 2 blocks/CU (proven best residency shape)
#define NB     (65536 / ROWS)   // 8192 blocks
#define PL     (D_ * 4)         // floats per LDS plane (3136): plane0 = rows 0-3, plane1 = rows 4-7
#define TAIL   (D_ - BLOCK)     // 16 tail features handled by threads 0..15

// tanh-approx GELU (|err| vs exact erf-GELU ~5e-4)
__device__ __forceinline__ float gelu_f(float x) {
    float x2    = x * x;
    float inner = fmaf(0.044715f * x, x2, x);
    float e     = exp2f(2.3022082f * inner);          // 2*sqrt(2/pi)*log2(e)
    float r     = __builtin_amdgcn_rcpf(e + 1.0f);
    return fmaf(-x, r, x);                            // x*e/(e+1)
}

__device__ __forceinline__ float4 gelu4(const float4& a) {
    return make_float4(gelu_f(a.x), gelu_f(a.y), gelu_f(a.z), gelu_f(a.w));
}

__device__ __forceinline__ void fma4(float4& a, const float4& h4, float wk) {
    a.x = fmaf(h4.x, wk, a.x);
    a.y = fmaf(h4.y, wk, a.y);
    a.z = fmaf(h4.z, wk, a.z);
    a.w = fmaf(h4.w, wk, a.w);
}

template <int K>
__device__ __forceinline__ void loadIdxW(const int* __restrict__ idx,
                                         const float* __restrict__ w,
                                         int n, int* jc, float* wc) {
    if constexpr (K == 2) {
        int2   j = *(const int2*)(idx + n * 2);
        float2 v = *(const float2*)(w + n * 2);
        jc[0] = j.x; jc[1] = j.y; wc[0] = v.x; wc[1] = v.y;
    } else if constexpr (K == 4) {
        int4   j = *(const int4*)(idx + n * 4);
        float4 v = *(const float4*)(w + n * 4);
        jc[0] = j.x; jc[1] = j.y; jc[2] = j.z; jc[3] = j.w;
        wc[0] = v.x; wc[1] = v.y; wc[2] = v.z; wc[3] = v.w;
    } else {
        int4   ja = *(const int4*)(idx + n * 8);
        int4   jb = *(const int4*)(idx + n * 8 + 4);
        float4 va = *(const float4*)(w + n * 8);
        float4 vb = *(const float4*)(w + n * 8 + 4);
        jc[0] = ja.x; jc[1] = ja.y; jc[2] = ja.z; jc[3] = ja.w;
        jc[4] = jb.x; jc[5] = jb.y; jc[6] = jb.z; jc[7] = jb.w;
        wc[0] = va.x; wc[1] = va.y; wc[2] = va.z; wc[3] = va.w;
        wc[4] = vb.x; wc[5] = vb.y; wc[6] = vb.z; wc[7] = vb.w;
    }
}

// One feature n, all 8 rows. Two-plane LDS: plane0 at [n*4], plane1 at [n*4+PL].
// Params loaded per phase (r8: hoisting across barriers starves the pipeline).
template <int K>
__device__ __forceinline__ void layer_one(const float* __restrict__ src,
                                          float* __restrict__ dst,
                                          const int* __restrict__ idx,
                                          const float* __restrict__ w,
                                          const float* __restrict__ bias,
                                          int n) {
    int   jc[K];
    float wc[K];
    loadIdxW<K>(idx, w, n, jc, wc);
    float  bc = bias[n];
    float4 lo = make_float4(bc, bc, bc, bc);
    float4 hi = lo;
#pragma unroll
    for (int k = 0; k < K; ++k) {
        const float* g = src + jc[k] * 4;
        float4 gl = *(const float4*)g;          // plane0
        float4 gh = *(const float4*)(g + PL);   // plane1, folded imm offset
        fma4(lo, gl, wc[k]);
        fma4(hi, gh, wc[k]);
    }
    *(float4*)(dst + n * 4)      = gelu4(lo);
    *(float4*)(dst + n * 4 + PL) = gelu4(hi);
}

__global__ __launch_bounds__(BLOCK)
void circnn_kernel(const float* __restrict__ x,
                   const int* __restrict__ idx1, const float* __restrict__ w1, const float* __restrict__ b1,
                   const int* __restrict__ idx2, const float* __restrict__ w2, const float* __restrict__ b2,
                   const int* __restrict__ idx3, const float* __restrict__ w3, const float* __restrict__ b3,
                   const float* __restrict__ fcw, const float* __restrict__ fcb,
                   float* __restrict__ out) {
    __shared__ __align__(16) float bufA[D_ * ROWS];   // 25,088 B: x, h2; then FC partials
    __shared__ __align__(16) float bufB[D_ * ROWS];   // 25,088 B: h1, h3
    __shared__ float logits[ROWS * NCLS];             // 320 B

    const int tid  = threadIdx.x;
    const int row0 = blockIdx.x * ROWS;

    // ---- Stage x -> bufA (two-plane): 8 strided-coalesced b32 reads -> 2 b128 writes
    const float* xb = x + (size_t)row0 * D_;
    {
        int n = tid;                      // n < 768 < 784, always valid
        float4 lo, hi;
        lo.x = xb[0 * D_ + n]; lo.y = xb[1 * D_ + n];
        lo.z = xb[2 * D_ + n]; lo.w = xb[3 * D_ + n];
        hi.x = xb[4 * D_ + n]; hi.y = xb[5 * D_ + n];
        hi.z = xb[6 * D_ + n]; hi.w = xb[7 * D_ + n];
        *(float4*)(bufA + n * 4)      = lo;
        *(float4*)(bufA + n * 4 + PL) = hi;
    }
    if (tid < TAIL) {
        int n = BLOCK + tid;
        float4 lo, hi;
        lo.x = xb[0 * D_ + n]; lo.y = xb[1 * D_ + n];
        lo.z = xb[2 * D_ + n]; lo.w = xb[3 * D_ + n];
        hi.x = xb[4 * D_ + n]; hi.y = xb[5 * D_ + n];
        hi.z = xb[6 * D_ + n]; hi.w = xb[7 * D_ + n];
        *(float4*)(bufA + n * 4)      = lo;
        *(float4*)(bufA + n * 4 + PL) = hi;
    }
    __syncthreads();

    // ---- Three sparse layers, ping-pong A->B->A->B, one barrier each
    layer_one<2>(bufA, bufB, idx1, w1, b1, tid);
    if (tid < TAIL) layer_one<2>(bufA, bufB, idx1, w1, b1, BLOCK + tid);
    __syncthreads();

    layer_one<4>(bufB, bufA, idx2, w2, b2, tid);
    if (tid < TAIL) layer_one<4>(bufB, bufA, idx2, w2, b2, BLOCK + tid);
    __syncthreads();

    layer_one<8>(bufA, bufB, idx3, w3, b3, tid);
    if (tid < TAIL) layer_one<8>(bufA, bufB, idx3, w3, b3, BLOCK + tid);
    __syncthreads();

    // ---- FC phase A: 512 threads (8 waves).
    //   p  = tid & 3        -> 4-way split of the 13 n-chunks (i = p, p+4, ...)
    //   qq = (tid >> 2) & 1 -> row half (plane)
    //   jj = tid >> 3       -> feature within chunk (0..63)
    // Reduce p-dim by two quad shfl_xor rounds on NAMED members (r5-proven:
    // no pointer casts -> facc stays in registers, no spill).
    float4* part4 = (float4*)bufA;    // layout [(jj*2+qq)*NCLS + c], 20,480 B
    if (tid < 512) {
        const int p  = tid & 3;
        const int qq = (tid >> 2) & 1;
        const int jj = tid >> 3;
        float4 facc[NCLS];
#pragma unroll
        for (int c = 0; c < NCLS; ++c) facc[c] = make_float4(0.f, 0.f, 0.f, 0.f);
#pragma unroll 1
        for (int i = p; i < 13; i += 4) {
            int n = jj + (i << 6);
            if (n < D_) {
                float4 hv = *(const float4*)(bufB + qq * PL + n * 4);
#pragma unroll
                for (int c = 0; c < NCLS; ++c)
                    fma4(facc[c], hv, fcw[c * D_ + n]);
            }
        }
#pragma unroll
        for (int c = 0; c < NCLS; ++c) {
            facc[c].x += __shfl_xor(facc[c].x, 1);
            facc[c].y += __shfl_xor(facc[c].y, 1);
            facc[c].z += __shfl_xor(facc[c].z, 1);
            facc[c].w += __shfl_xor(facc[c].w, 1);
            facc[c].x += __shfl_xor(facc[c].x, 2);
            facc[c].y += __shfl_xor(facc[c].y, 2);
            facc[c].z += __shfl_xor(facc[c].z, 2);
            facc[c].w += __shfl_xor(facc[c].w, 2);
        }
        if (p == 0) {
#pragma unroll
            for (int c = 0; c < NCLS; ++c)
                part4[(jj * 2 + qq) * NCLS + c] = facc[c];
        }
    }
    __syncthreads();

    // ---- FC phase B: 640 threads (10 full waves). tid = rc*8 + s:
    //   s  = tid & 7  -> 8-way split of the 64 jj-partials (8 each)
    //   rc = tid >> 3 -> (r, c) pair, 0..79
    // Reduce s-dim by three shfl_xor rounds (named scalar, lanes contiguous).
    if (tid < 640) {
        const int s  = tid & 7;
        const int rc = tid >> 3;
        const int r  = rc / NCLS, c = rc - r * NCLS;
        const int qq = r >> 2, comp = r & 3;
        const float* pf = (const float*)part4;
        float acc = 0.f;
#pragma unroll
        for (int j8 = 0; j8 < 8; ++j8) {
            int jj = s * 8 + j8;
            acc += pf[((jj * 2 + qq) * NCLS + c) * 4 + comp];
        }
        acc += __shfl_xor(acc, 1);
        acc += __shfl_xor(acc, 2);
        acc += __shfl_xor(acc, 4);
        if (s == 0) logits[rc] = acc + fcb[c];
    }
    __syncthreads();

    // ---- softmax (redundant per-(r,c) thread), coalesced 80-float store
    if (tid < ROWS * NCLS) {
        int r = tid / NCLS;
        const float* lg = logits + r * NCLS;
        float m = lg[0];
#pragma unroll
        for (int c = 1; c < NCLS; ++c) m = fmaxf(m, lg[c]);
        float s = 0.f;
#pragma unroll
        for (int c = 0; c < NCLS; ++c) s += __expf(lg[c] - m);
        out[(size_t)row0 * NCLS + tid] = __expf(logits[tid] - m) / s;
    }
}

extern "C" void kernel_launch(void* const* d_in, const int* in_sizes, int n_in,
                              void* d_out, int out_size, void* d_ws, size_t ws_size,
                              hipStream_t stream) {
    const float* x    = (const float*)d_in[0];
    const int*   idx1 = (const int*)d_in[1];
    const float* w1   = (const float*)d_in[2];
    const float* b1   = (const float*)d_in[3];
    const int*   idx2 = (const int*)d_in[4];
    const float* w2   = (const float*)d_in[5];
    const float* b2   = (const float*)d_in[6];
    const int*   idx3 = (const int*)d_in[7];
    const float* w3   = (const float*)d_in[8];
    const float* b3   = (const float*)d_in[9];
    const float* fcw  = (const float*)d_in[10];
    const float* fcb  = (const float*)d_in[11];
    float* out = (float*)d_out;

    circnn_kernel<<<dim3(NB), dim3(BLOCK), 0, stream>>>(
        x, idx1, w1, b1, idx2, w2, b2, idx3, w3, b3, fcw, fcb, out);
}

// Round 13
// 424.209 us; speedup vs baseline: 1.2875x; 1.2875x over previous
//
#include <hip/hip_runtime.h>

#define D_     784
#define ROWS   8
#define NCLS   10
#define BLOCK  768              // 12 waves; 2 blocks/CU (proven best residency shape)
#define NB     (65536 / ROWS)   // 8192 blocks
// Four half-planes of float2 per feature (8B granules -> 16 bank-pair positions,
// halving the random-gather balls-in-bins load vs 16B granules' 8 positions).
// Sub-plane stride 1570 dwords (= 1568 payload + 2 pad; pad shifts banks by 2).
#define SP     1570
#define OXY0   0                // rows 0,1
#define OZW0   (SP)             // rows 2,3
#define OXY1   (2 * SP)         // rows 4,5
#define OZW1   (3 * SP)         // rows 6,7
#define BUFSZ  (4 * SP)         // 6280 floats = 25,120 B per buffer
#define TAIL   (D_ - BLOCK)     // 16 tail features handled by threads 0..15

// tanh-approx GELU (|err| vs exact erf-GELU ~5e-4)
__device__ __forceinline__ float gelu_f(float x) {
    float x2    = x * x;
    float inner = fmaf(0.044715f * x, x2, x);
    float e     = exp2f(2.3022082f * inner);          // 2*sqrt(2/pi)*log2(e)
    float r     = __builtin_amdgcn_rcpf(e + 1.0f);
    return fmaf(-x, r, x);                            // x*e/(e+1)
}

__device__ __forceinline__ float2 gelu2(const float2& a) {
    return make_float2(gelu_f(a.x), gelu_f(a.y));
}

__device__ __forceinline__ void fma2(float2& a, const float2& h2, float wk) {
    a.x = fmaf(h2.x, wk, a.x);
    a.y = fmaf(h2.y, wk, a.y);
}

template <int K>
__device__ __forceinline__ void loadIdxW(const int* __restrict__ idx,
                                         const float* __restrict__ w,
                                         int n, int* jc, float* wc) {
    if constexpr (K == 2) {
        int2   j = *(const int2*)(idx + n * 2);
        float2 v = *(const float2*)(w + n * 2);
        jc[0] = j.x; jc[1] = j.y; wc[0] = v.x; wc[1] = v.y;
    } else if constexpr (K == 4) {
        int4   j = *(const int4*)(idx + n * 4);
        float4 v = *(const float4*)(w + n * 4);
        jc[0] = j.x; jc[1] = j.y; jc[2] = j.z; jc[3] = j.w;
        wc[0] = v.x; wc[1] = v.y; wc[2] = v.z; wc[3] = v.w;
    } else {
        int4   ja = *(const int4*)(idx + n * 8);
        int4   jb = *(const int4*)(idx + n * 8 + 4);
        float4 va = *(const float4*)(w + n * 8);
        float4 vb = *(const float4*)(w + n * 8 + 4);
        jc[0] = ja.x; jc[1] = ja.y; jc[2] = ja.z; jc[3] = ja.w;
        jc[4] = jb.x; jc[5] = jb.y; jc[6] = jb.z; jc[7] = jb.w;
        wc[0] = va.x; wc[1] = va.y; wc[2] = va.z; wc[3] = va.w;
        wc[4] = vb.x; wc[5] = vb.y; wc[6] = vb.z; wc[7] = vb.w;
    }
}

// One feature n, all 8 rows as 4 float2 sub-accumulators. Gathers are 4x
// ds_read_b64 (8B granules, offsets folded to imm). Params loaded per phase
// (r8: hoisting across barriers starves the pipeline). No shuffles (r12).
template <int K>
__device__ __forceinline__ void layer_one(const float* __restrict__ src,
                                          float* __restrict__ dst,
                                          const int* __restrict__ idx,
                                          const float* __restrict__ w,
                                          const float* __restrict__ bias,
                                          int n) {
    int   jc[K];
    float wc[K];
    loadIdxW<K>(idx, w, n, jc, wc);
    float  bc  = bias[n];
    float2 a01 = make_float2(bc, bc);
    float2 a23 = a01, a45 = a01, a67 = a01;
#pragma unroll
    for (int k = 0; k < K; ++k) {
        const float* g = src + jc[k] * 2;
        float2 g01 = *(const float2*)(g + OXY0);
        float2 g23 = *(const float2*)(g + OZW0);
        float2 g45 = *(const float2*)(g + OXY1);
        float2 g67 = *(const float2*)(g + OZW1);
        fma2(a01, g01, wc[k]);
        fma2(a23, g23, wc[k]);
        fma2(a45, g45, wc[k]);
        fma2(a67, g67, wc[k]);
    }
    float* d = dst + n * 2;
    *(float2*)(d + OXY0) = gelu2(a01);
    *(float2*)(d + OZW0) = gelu2(a23);
    *(float2*)(d + OXY1) = gelu2(a45);
    *(float2*)(d + OZW1) = gelu2(a67);
}

__global__ __launch_bounds__(BLOCK)
void circnn_kernel(const float* __restrict__ x,
                   const int* __restrict__ idx1, const float* __restrict__ w1, const float* __restrict__ b1,
                   const int* __restrict__ idx2, const float* __restrict__ w2, const float* __restrict__ b2,
                   const int* __restrict__ idx3, const float* __restrict__ w3, const float* __restrict__ b3,
                   const float* __restrict__ fcw, const float* __restrict__ fcb,
                   float* __restrict__ out) {
    __shared__ __align__(16) float bufA[BUFSZ];       // 25,120 B: x, h2; then FC partials
    __shared__ __align__(16) float bufB[BUFSZ];       // 25,120 B: h1, h3
    __shared__ float logits[ROWS * NCLS];             // 320 B

    const int tid  = threadIdx.x;
    const int row0 = blockIdx.x * ROWS;

    // ---- Stage x -> bufA: 8 strided-coalesced b32 reads -> 4 b64 writes
    const float* xb = x + (size_t)row0 * D_;
    {
        int n = tid;                      // n < 768 < 784, always valid
        float* d = bufA + n * 2;
        *(float2*)(d + OXY0) = make_float2(xb[0 * D_ + n], xb[1 * D_ + n]);
        *(float2*)(d + OZW0) = make_float2(xb[2 * D_ + n], xb[3 * D_ + n]);
        *(float2*)(d + OXY1) = make_float2(xb[4 * D_ + n], xb[5 * D_ + n]);
        *(float2*)(d + OZW1) = make_float2(xb[6 * D_ + n], xb[7 * D_ + n]);
    }
    if (tid < TAIL) {
        int n = BLOCK + tid;
        float* d = bufA + n * 2;
        *(float2*)(d + OXY0) = make_float2(xb[0 * D_ + n], xb[1 * D_ + n]);
        *(float2*)(d + OZW0) = make_float2(xb[2 * D_ + n], xb[3 * D_ + n]);
        *(float2*)(d + OXY1) = make_float2(xb[4 * D_ + n], xb[5 * D_ + n]);
        *(float2*)(d + OZW1) = make_float2(xb[6 * D_ + n], xb[7 * D_ + n]);
    }
    __syncthreads();

    // ---- Three sparse layers, ping-pong A->B->A->B, one barrier each
    layer_one<2>(bufA, bufB, idx1, w1, b1, tid);
    if (tid < TAIL) layer_one<2>(bufA, bufB, idx1, w1, b1, BLOCK + tid);
    __syncthreads();

    layer_one<4>(bufB, bufA, idx2, w2, b2, tid);
    if (tid < TAIL) layer_one<4>(bufB, bufA, idx2, w2, b2, BLOCK + tid);
    __syncthreads();

    layer_one<8>(bufA, bufB, idx3, w3, b3, tid);
    if (tid < TAIL) layer_one<8>(bufA, bufB, idx3, w3, b3, BLOCK + tid);
    __syncthreads();

    // ---- FC phase A: 128 threads, r2-gold form (no shuffles, no pointer casts;
    // facc in registers via member access only).
    float4* part4 = (float4*)bufA;    // layout [(jj*2+qq)*NCLS + c], 20,464 B <= bufA
    if (tid < 128) {
        const int jj = tid >> 1;      // 0..63
        const int qq = tid & 1;       // row half: 0 -> rows 0-3, 1 -> rows 4-7
        const int oa = qq ? OXY1 : OXY0;   // first two rows of the half
        const int ob = qq ? OZW1 : OZW0;   // last two rows of the half
        float4 facc[NCLS];
#pragma unroll
        for (int c = 0; c < NCLS; ++c) facc[c] = make_float4(0.f, 0.f, 0.f, 0.f);
#pragma unroll 1
        for (int i = 0; i < 13; ++i) {
            int n = jj + 64 * i;
            if (n < D_) {
                float2 ha = *(const float2*)(bufB + oa + n * 2);
                float2 hb = *(const float2*)(bufB + ob + n * 2);
#pragma unroll
                for (int c = 0; c < NCLS; ++c) {
                    float wk = fcw[c * D_ + n];
                    facc[c].x = fmaf(ha.x, wk, facc[c].x);
                    facc[c].y = fmaf(ha.y, wk, facc[c].y);
                    facc[c].z = fmaf(hb.x, wk, facc[c].z);
                    facc[c].w = fmaf(hb.y, wk, facc[c].w);
                }
            }
        }
#pragma unroll
        for (int c = 0; c < NCLS; ++c)
            part4[(jj * 2 + qq) * NCLS + c] = facc[c];
    }
    __syncthreads();

    // ---- FC phase B: 80 threads (r, c) sum 64 jj-partials -> logits
    if (tid < ROWS * NCLS) {
        int r = tid / NCLS, c = tid - r * NCLS;
        int qq = r >> 2, comp = r & 3;
        const float* pf = (const float*)part4;
        float s = fcb[c];
#pragma unroll 4
        for (int jj = 0; jj < 64; ++jj)
            s += pf[((jj * 2 + qq) * NCLS + c) * 4 + comp];
        logits[tid] = s;
    }
    __syncthreads();

    // ---- softmax (redundant per-(r,c) thread), coalesced 80-float store
    if (tid < ROWS * NCLS) {
        int r = tid / NCLS;
        const float* lg = logits + r * NCLS;
        float m = lg[0];
#pragma unroll
        for (int c = 1; c < NCLS; ++c) m = fmaxf(m, lg[c]);
        float s = 0.f;
#pragma unroll
        for (int c = 0; c < NCLS; ++c) s += __expf(lg[c] - m);
        out[(size_t)row0 * NCLS + tid] = __expf(logits[tid] - m) / s;
    }
}

extern "C" void kernel_launch(void* const* d_in, const int* in_sizes, int n_in,
                              void* d_out, int out_size, void* d_ws, size_t ws_size,
                              hipStream_t stream) {
    const float* x    = (const float*)d_in[0];
    const int*   idx1 = (const int*)d_in[1];
    const float* w1   = (const float*)d_in[2];
    const float* b1   = (const float*)d_in[3];
    const int*   idx2 = (const int*)d_in[4];
    const float* w2   = (const float*)d_in[5];
    const float* b2   = (const float*)d_in[6];
    const int*   idx3 = (const int*)d_in[7];
    const float* w3   = (const float*)d_in[8];
    const float* b3   = (const float*)d_in[9];
    const float* fcw  = (const float*)d_in[10];
    const float* fcb  = (const float*)d_in[11];
    float* out = (float*)d_out;

    circnn_kernel<<<dim3(NB), dim3(BLOCK), 0, stream>>>(
        x, idx1, w1, b1, idx2, w2, b2, idx3, w3, b3, fcw, fcb, out);
}